// Round 1
// baseline (6807.400 us; speedup 1.0000x reference)
//
#include <hip/hip_runtime.h>
#include <math.h>

// LorentzMLA — correctness-first f32 implementation.
// B=1, S=2048, DIM=2048, H=16, NOPE=128, ROPE=65 (ROPE_SP=64), QK_HD=193,
// KV_RANK=512, VHD=128. Causal mask is hard-coded (mask input is triu k=1).
//
// Workspace layout (floats), total 32,671,744 floats = ~124.6 MiB:
//   q_raw  [S][3072]          @ 0          (6291456)   -> reused for attn_out [S][2048]
//   kvbuf  [S][576]/[S][4080] @ 6291456    (8355840)   -> kv_full then kvb, reused for y [S][2047]
//   kv_pt  [S][513]           @ 14647296   (1050624)
//   k_pe   [S][64]            @ 15697920   (131072)
//   q_proj [H][S][193]        @ 15828992   (6324224)
//   k_proj [H][S][193]        @ 22153216   (6324224)
//   v_proj [H][S][128]        @ 28477440   (4194304)

#define S_LEN 2048
#define NH 16

// ---------------- generic f32 GEMM: C[M][N] = A[M][K] @ B[K][N] (row-major) ----
__global__ __launch_bounds__(256) void gemm_f32(
    const float* __restrict__ A, const float* __restrict__ B, float* __restrict__ C,
    int M, int N, int K)
{
  __shared__ float As[16][65];
  __shared__ float Bs[16][65];
  const int bm = blockIdx.y * 64, bn = blockIdx.x * 64;
  const int tid = threadIdx.x;
  const int tr = tid >> 4, tc = tid & 15;
  float acc[4][4] = {};
  for (int k0 = 0; k0 < K; k0 += 16) {
    #pragma unroll
    for (int i = tid; i < 64 * 16; i += 256) {
      int mm = i >> 4, kk = i & 15;
      float v = 0.f;
      if (k0 + kk < K) v = A[(size_t)(bm + mm) * K + k0 + kk];
      As[kk][mm] = v;
    }
    #pragma unroll
    for (int i = tid; i < 16 * 64; i += 256) {
      int kk = i >> 6, nn = i & 63;
      float v = 0.f;
      if (k0 + kk < K && bn + nn < N) v = B[(size_t)(k0 + kk) * N + bn + nn];
      Bs[kk][nn] = v;
    }
    __syncthreads();
    #pragma unroll
    for (int kk = 0; kk < 16; ++kk) {
      float a[4], b[4];
      #pragma unroll
      for (int i = 0; i < 4; ++i) a[i] = As[kk][tr * 4 + i];
      #pragma unroll
      for (int j = 0; j < 4; ++j) b[j] = Bs[kk][tc * 4 + j];
      #pragma unroll
      for (int i = 0; i < 4; ++i)
        #pragma unroll
        for (int j = 0; j < 4; ++j) acc[i][j] += a[i] * b[j];
    }
    __syncthreads();
  }
  #pragma unroll
  for (int i = 0; i < 4; ++i) {
    int row = bm + tr * 4 + i;
    if (row < M) {
      #pragma unroll
      for (int j = 0; j < 4; ++j) {
        int col = bn + tc * 4 + j;
        if (col < N) C[(size_t)row * N + col] = acc[i][j];
      }
    }
  }
}

// ---------------- q_raw -> rotary(pe) + project -> q_proj [H][S][193] ----------
__global__ __launch_bounds__(64) void build_qproj(
    const float* __restrict__ qraw,               // [S][3072]
    const float* __restrict__ fc, const float* __restrict__ fs,  // [S][32]
    float* __restrict__ qp)                       // [H][S][193]
{
  const int s = blockIdx.x, h = blockIdx.y;
  const int lane = threadIdx.x;                   // 64
  const float* src = qraw + (size_t)s * 3072 + h * 192;
  float* dst = qp + ((size_t)h * S_LEN + s) * 193;
  float e0 = src[lane];
  float e1 = src[lane + 64];
  dst[1 + lane] = e0;
  dst[1 + lane + 64] = e1;
  float sq = e0 * e0 + e1 * e1;
  if (lane < 32) {
    float x0 = src[128 + 2 * lane], x1 = src[129 + 2 * lane];
    float c = fc[(size_t)s * 32 + lane], sn = fs[(size_t)s * 32 + lane];
    float y0 = x0 * c - x1 * sn;
    float y1 = x0 * sn + x1 * c;
    dst[1 + 128 + 2 * lane] = y0;
    dst[1 + 129 + 2 * lane] = y1;
    sq += y0 * y0 + y1 * y1;
  }
  #pragma unroll
  for (int off = 32; off; off >>= 1) sq += __shfl_down(sq, off);
  if (lane == 0) dst[0] = sqrtf(sq + 1.0f);
}

// ---------------- kv_full -> rmsnorm+project(kv_pt), rotary(k_pe) --------------
__global__ __launch_bounds__(256) void build_kvpt(
    const float* __restrict__ kvfull,   // [S][576]
    const float* __restrict__ gamma,    // [512]
    const float* __restrict__ fc, const float* __restrict__ fs,  // [S][32]
    float* __restrict__ kvpt,           // [S][513]
    float* __restrict__ kpe)            // [S][64]
{
  const int s = blockIdx.x;
  const int tid = threadIdx.x;          // 256
  const int wave = tid >> 6, lane = tid & 63;
  const float* src = kvfull + (size_t)s * 576;
  __shared__ float red1[4], red2[4];
  float v0 = src[tid], v1 = src[tid + 256];
  float sq = v0 * v0 + v1 * v1;
  #pragma unroll
  for (int off = 32; off; off >>= 1) sq += __shfl_down(sq, off);
  if (lane == 0) red1[wave] = sq;
  __syncthreads();
  float tot = red1[0] + red1[1] + red1[2] + red1[3];
  float rms_inv = 1.0f / sqrtf(tot * (1.0f / 512.0f) + 1e-6f);
  float n0 = v0 * rms_inv * gamma[tid];
  float n1 = v1 * rms_inv * gamma[tid + 256];
  float sq2 = n0 * n0 + n1 * n1;
  #pragma unroll
  for (int off = 32; off; off >>= 1) sq2 += __shfl_down(sq2, off);
  if (lane == 0) red2[wave] = sq2;
  __syncthreads();
  float* dst = kvpt + (size_t)s * 513;
  dst[1 + tid] = n0;
  dst[1 + tid + 256] = n1;
  if (tid == 0) dst[0] = sqrtf(red2[0] + red2[1] + red2[2] + red2[3] + 1.0f);
  if (tid < 32) {
    float x0 = src[512 + 2 * tid], x1 = src[513 + 2 * tid];
    float c = fc[(size_t)s * 32 + tid], sn = fs[(size_t)s * 32 + tid];
    kpe[(size_t)s * 64 + 2 * tid]     = x0 * c - x1 * sn;
    kpe[(size_t)s * 64 + 2 * tid + 1] = x0 * sn + x1 * c;
  }
}

// ---------------- kvb -> k_proj [H][S][193], v_proj [H][S][128] ----------------
__global__ __launch_bounds__(64) void build_kvproj(
    const float* __restrict__ kvb,   // [S][4080]
    const float* __restrict__ kpe,   // [S][64]
    float* __restrict__ kp,          // [H][S][193]
    float* __restrict__ vp)          // [H][S][128]
{
  const int s = blockIdx.x, h = blockIdx.y;
  const int lane = threadIdx.x;      // 64
  const float* src = kvb + (size_t)s * 4080 + h * 255;
  float* kdst = kp + ((size_t)h * S_LEN + s) * 193;
  float* vdst = vp + ((size_t)h * S_LEN + s) * 128;
  float a0 = src[lane], a1 = src[lane + 64];
  float pe = kpe[(size_t)s * 64 + lane];
  kdst[1 + lane] = a0;
  kdst[1 + lane + 64] = a1;
  kdst[1 + 128 + lane] = pe;
  float sq = a0 * a0 + a1 * a1 + pe * pe;
  #pragma unroll
  for (int off = 32; off; off >>= 1) sq += __shfl_down(sq, off);
  if (lane == 0) kdst[0] = sqrtf(sq + 1.0f);
  float b0 = src[128 + lane];
  float b1 = (lane < 63) ? src[192 + lane] : 0.f;
  vdst[1 + lane] = b0;
  if (lane < 63) vdst[65 + lane] = b1;
  float sqv = b0 * b0 + b1 * b1;
  #pragma unroll
  for (int off = 32; off; off >>= 1) sqv += __shfl_down(sqv, off);
  if (lane == 0) vdst[0] = sqrtf(sqv + 1.0f);
}

// ---------------- causal attention + Lorentz centroid epilogue -----------------
#define QTILE 32
#define KTILE 32
__global__ __launch_bounds__(256) void attn_kernel(
    const float* __restrict__ qp,    // [H][S][193]
    const float* __restrict__ kp,    // [H][S][193]
    const float* __restrict__ vp,    // [H][S][128]
    const float* __restrict__ ss, const float* __restrict__ bp,
    float* __restrict__ out)         // [S][H*128]
{
  const int h = blockIdx.y;
  const int q0 = blockIdx.x * QTILE;
  const int tid = threadIdx.x;
  const float inv_scale = 1.0f / ss[0];
  const float bias = bp[0];

  __shared__ float Qs[QTILE][193];
  __shared__ float Ks[KTILE][193];
  __shared__ float Vs[KTILE][128];
  __shared__ float Os[QTILE][129];
  __shared__ float Sc[QTILE][33];
  __shared__ float mArr[QTILE], lArr[QTILE], aArr[QTILE];

  const float* qbase = qp + ((size_t)h * S_LEN + q0) * 193;
  for (int i = tid; i < QTILE * 193; i += 256) {
    int r = i / 193, d = i % 193;
    float v = qbase[(size_t)r * 193 + d];
    if (d == 0) v = -v;             // signs: time component negated (Minkowski)
    Qs[r][d] = v;
  }
  for (int i = tid; i < QTILE * 128; i += 256) Os[i >> 7][i & 127] = 0.f;
  if (tid < QTILE) { mArr[tid] = -INFINITY; lArr[tid] = 0.f; }
  __syncthreads();

  const int ntile = q0 / KTILE + 1;    // causal: keys <= q0+31
  for (int t = 0; t < ntile; ++t) {
    const int k0 = t * KTILE;
    const float* kbase = kp + ((size_t)h * S_LEN + k0) * 193;
    for (int i = tid; i < KTILE * 193; i += 256) {
      int r = i / 193, d = i % 193;
      Ks[r][d] = kbase[(size_t)r * 193 + d];
    }
    const float* vbase = vp + ((size_t)h * S_LEN + k0) * 128;
    for (int i = tid; i < KTILE * 128; i += 256) {
      int r = i >> 7, d = i & 127;
      Vs[r][d] = vbase[(size_t)r * 128 + d];
    }
    __syncthreads();

    // scores
    for (int i = tid; i < QTILE * KTILE; i += 256) {
      int r = i >> 5, j = i & 31;
      float acc = 0.f;
      for (int d = 0; d < 193; ++d) acc += Qs[r][d] * Ks[j][d];
      float sv = (2.0f + 2.0f * acc) * inv_scale + bias;
      if (k0 + j > q0 + r) sv = -INFINITY;   // causal mask
      Sc[r][j] = sv;
    }
    __syncthreads();

    // online softmax update (one thread per row)
    if (tid < QTILE) {
      const int r = tid;
      float mold = mArr[r], mnew = mold;
      #pragma unroll
      for (int j = 0; j < KTILE; ++j) mnew = fmaxf(mnew, Sc[r][j]);
      float alpha = expf(mold - mnew);     // mold=-inf -> 0 (mnew finite after tile 0)
      float lsum = 0.f;
      #pragma unroll
      for (int j = 0; j < KTILE; ++j) {
        float p = expf(Sc[r][j] - mnew);
        Sc[r][j] = p;
        lsum += p;
      }
      lArr[r] = lArr[r] * alpha + lsum;
      mArr[r] = mnew;
      aArr[r] = alpha;
    }
    __syncthreads();

    // O = O*alpha + P @ V
    for (int i = tid; i < QTILE * 128; i += 256) {
      int r = i >> 7, d = i & 127;
      float o = Os[r][d] * aArr[r];
      #pragma unroll
      for (int j = 0; j < KTILE; ++j) o += Sc[r][j] * Vs[j][d];
      Os[r][d] = o;
    }
    __syncthreads();
  }

  // epilogue: ave = O/l ; cen = ave / sqrt(clip(|Minkowski(ave)|, 1e-8))
  if (tid < QTILE) {
    const int r = tid;
    float linv = 1.0f / lArr[r];
    float a0 = Os[r][0] * linv;
    float inner = -a0 * a0;
    for (int d = 1; d < 128; ++d) {
      float a = Os[r][d] * linv;
      inner += a * a;
    }
    float sc = 1.0f / sqrtf(fmaxf(fabsf(inner), 1e-8f));
    float* ob = out + (size_t)(q0 + r) * 2048 + h * 128;
    for (int d = 0; d < 128; ++d) ob[d] = Os[r][d] * linv * sc;
  }
}

// ---------------- final projection: out = [sqrt(|y|^2+1), y] ------------------
__global__ __launch_bounds__(256) void final_project(
    const float* __restrict__ y,   // [S][2047]
    float* __restrict__ out)       // [S][2048]
{
  const int s = blockIdx.x, tid = threadIdx.x;
  const int wave = tid >> 6, lane = tid & 63;
  const float* src = y + (size_t)s * 2047;
  float* dst = out + (size_t)s * 2048;
  float sq = 0.f;
  for (int j = tid; j < 2047; j += 256) {
    float v = src[j];
    dst[1 + j] = v;
    sq += v * v;
  }
  __shared__ float red[4];
  #pragma unroll
  for (int off = 32; off; off >>= 1) sq += __shfl_down(sq, off);
  if (lane == 0) red[wave] = sq;
  __syncthreads();
  if (tid == 0) dst[0] = sqrtf(red[0] + red[1] + red[2] + red[3] + 1.0f);
}

extern "C" void kernel_launch(void* const* d_in, const int* in_sizes, int n_in,
                              void* d_out, int out_size, void* d_ws, size_t ws_size,
                              hipStream_t stream) {
  const float* x    = (const float*)d_in[0];
  // d_in[1] = start_pos (unused, always 0)
  const float* fc   = (const float*)d_in[2];
  const float* fs   = (const float*)d_in[3];
  // d_in[4] = mask (unused, causal hard-coded)
  const float* wq   = (const float*)d_in[5];
  const float* wkva = (const float*)d_in[6];
  const float* gam  = (const float*)d_in[7];
  const float* wkvb = (const float*)d_in[8];
  const float* wo   = (const float*)d_in[9];
  const float* ssp  = (const float*)d_in[10];
  const float* bpp  = (const float*)d_in[11];
  float* out = (float*)d_out;
  float* ws  = (float*)d_ws;

  float* q_raw  = ws + 0;              // [2048][3072]
  float* kvbuf  = ws + 6291456;        // [2048][576] then [2048][4080]
  float* kv_pt  = ws + 14647296;       // [2048][513]
  float* k_pe   = ws + 15697920;       // [2048][64]
  float* q_proj = ws + 15828992;       // [16][2048][193]
  float* k_proj = ws + 22153216;       // [16][2048][193]
  float* v_proj = ws + 28477440;       // [16][2048][128]
  float* attn_o = q_raw;               // reuse: [2048][2048]
  float* ybuf   = kvbuf;               // reuse: [2048][2047]

  // 1) q_raw = x @ wq_w  (2048x2048 @ 2048x3072)
  gemm_f32<<<dim3(3072 / 64, 2048 / 64), 256, 0, stream>>>(x, wq, q_raw, 2048, 3072, 2048);
  // 2) kv_full = x @ wkv_a_w  (2048x2048 @ 2048x576)
  gemm_f32<<<dim3(9, 32), 256, 0, stream>>>(x, wkva, kvbuf, 2048, 576, 2048);
  // 3) rmsnorm + project kv, rotary k_pe
  build_kvpt<<<dim3(2048), 256, 0, stream>>>(kvbuf, gam, fc, fs, kv_pt, k_pe);
  // 4) kvb = kv_pt @ wkv_b_w  (2048x513 @ 513x4080)
  gemm_f32<<<dim3(64, 32), 256, 0, stream>>>(kv_pt, wkvb, kvbuf, 2048, 4080, 513);
  // 5) q_proj: rotary + Lorentz project
  build_qproj<<<dim3(2048, 16), 64, 0, stream>>>(q_raw, fc, fs, q_proj);
  // 6) k_proj / v_proj
  build_kvproj<<<dim3(2048, 16), 64, 0, stream>>>(kvbuf, k_pe, k_proj, v_proj);
  // 7) causal attention + centroid epilogue -> attn_o [2048][2048]
  attn_kernel<<<dim3(S_LEN / QTILE, NH), 256, 0, stream>>>(q_proj, k_proj, v_proj, ssp, bpp, attn_o);
  // 8) y = attn_o @ wo_w  (2048x2048 @ 2048x2047)
  gemm_f32<<<dim3(32, 32), 256, 0, stream>>>(attn_o, wo, ybuf, 2048, 2047, 2048);
  // 9) final Lorentz projection -> d_out [2048][2048]
  final_project<<<dim3(2048), 256, 0, stream>>>(ybuf, out);
}

// Round 2
// 571.408 us; speedup vs baseline: 11.9134x; 11.9134x over previous
//
#include <hip/hip_runtime.h>
#include <math.h>

// LorentzMLA — bf16 MFMA implementation.
// S=2048, DIM=2048, H=16, NOPE=128, ROPE_SP=64, QK_HD=193 (pad 224),
// KV_RANK=512 (kv_pt 513 pad 544), VHD=128. Causal mask hard-coded.
// All GEMMs: A[M][K] bf16 x BT[N][K] bf16 -> C[M][N] bf16 (f32 MFMA accum).

typedef unsigned short u16;
typedef unsigned int u32;
typedef __attribute__((ext_vector_type(8))) short bf16x8;
typedef __attribute__((ext_vector_type(4))) float f32x4;

#define S_LEN 2048
#define NH 16
#define DPAD 224

__device__ __forceinline__ u16 f2bf(float f){
  u32 u = __builtin_bit_cast(u32, f);
  u32 r = u + 0x7fffu + ((u >> 16) & 1u);
  return (u16)(r >> 16);
}
__device__ __forceinline__ float bf2f(u16 h){
  u32 u = ((u32)h) << 16;
  return __builtin_bit_cast(float, u);
}

// ---------------- f32 -> bf16 cast, 8 elems/thread ----------------------------
__global__ __launch_bounds__(256) void cast_bf16x8(
    const float* __restrict__ in, u16* __restrict__ out)
{
  size_t i = ((size_t)blockIdx.x*256 + threadIdx.x)*8;
  float4 a = *(const float4*)(in + i);
  float4 b = *(const float4*)(in + i + 4);
  uint4 v;
  v.x = (u32)f2bf(a.x) | ((u32)f2bf(a.y) << 16);
  v.y = (u32)f2bf(a.z) | ((u32)f2bf(a.w) << 16);
  v.z = (u32)f2bf(b.x) | ((u32)f2bf(b.y) << 16);
  v.w = (u32)f2bf(b.z) | ((u32)f2bf(b.w) << 16);
  *(uint4*)(out + i) = v;
}

// ---------------- transpose + cast + zero-pad: out[n][k] = in[k][n] -----------
__global__ void transpose_cast(const float* __restrict__ in, u16* __restrict__ out,
                               int R, int Cc, int outR, int outC)
{
  __shared__ float t[32][33];
  const int tx = threadIdx.x, ty = threadIdx.y;
  const int bx = blockIdx.x*32, by = blockIdx.y*32;
  #pragma unroll
  for (int i=0;i<4;++i){
    int r = bx + ty + i*8, c = by + tx;
    t[ty+i*8][tx] = (r<R && c<Cc) ? in[(size_t)r*Cc + c] : 0.f;
  }
  __syncthreads();
  #pragma unroll
  for (int i=0;i<4;++i){
    int orow = by + ty + i*8, ocol = bx + tx;
    if (orow<outR && ocol<outC) out[(size_t)orow*outC + ocol] = f2bf(t[tx][ty+i*8]);
  }
}

// ---------------- bf16 MFMA GEMM: C[M][N] = A[M][K] @ BT[N][K]^T ---------------
// 128x128 tile, BK=32, 4 waves (2x2 of 64x64), reg-prefetch, XOR-swizzled LDS.
__global__ __launch_bounds__(256) void gemm_bf16(
    const u16* __restrict__ A, const u16* __restrict__ BT, u16* __restrict__ C,
    int M, int N, int K)
{
  __shared__ __align__(16) u16 As[128*32];
  __shared__ __align__(16) u16 Bs[128*32];
  const int tid = threadIdx.x;
  const int bm = blockIdx.y*128, bn = blockIdx.x*128;
  const int w = tid>>6, lane = tid&63, lg = lane>>4, li = lane&15;
  const int wr = w>>1, wc = w&1;
  const int srow = tid>>2, q = tid&3;
  const int swz = (q ^ (srow&3)) << 3;          // pre-swizzled store slot

  const u16* Ap  = A  + (size_t)(bm+srow)*K + q*8;
  const u16* Ap2 = Ap + (size_t)64*K;
  const u16* Bp  = BT + (size_t)(bn+srow)*K + q*8;
  const u16* Bp2 = Bp + (size_t)64*K;
  u16* aw  = &As[srow*32 + swz];
  u16* aw2 = &As[(srow+64)*32 + swz];
  u16* bw  = &Bs[srow*32 + swz];
  u16* bw2 = &Bs[(srow+64)*32 + swz];
  const int rsw = (lg ^ (li&3)) << 3;           // swizzled read slot
  const u16* ar = &As[(wr*64+li)*32 + rsw];
  const u16* br = &Bs[(wc*64+li)*32 + rsw];

  f32x4 acc[4][4];
  #pragma unroll
  for (int m=0;m<4;++m)
    #pragma unroll
    for (int n=0;n<4;++n) acc[m][n] = (f32x4){0.f,0.f,0.f,0.f};

  const int nk = K >> 5;
  bf16x8 ra  = *(const bf16x8*)Ap;
  bf16x8 ra2 = *(const bf16x8*)Ap2;
  bf16x8 rb  = *(const bf16x8*)Bp;
  bf16x8 rb2 = *(const bf16x8*)Bp2;
  for (int kt=0; kt<nk; ++kt){
    __syncthreads();                 // prev-tile reads done
    *(bf16x8*)aw = ra;  *(bf16x8*)aw2 = ra2;
    *(bf16x8*)bw = rb;  *(bf16x8*)bw2 = rb2;
    __syncthreads();
    if (kt+1 < nk){                  // prefetch next tile (in flight during MFMA)
      const int ko = (kt+1)*32;
      ra  = *(const bf16x8*)(Ap+ko);  ra2 = *(const bf16x8*)(Ap2+ko);
      rb  = *(const bf16x8*)(Bp+ko);  rb2 = *(const bf16x8*)(Bp2+ko);
    }
    bf16x8 af[4], bg[4];
    #pragma unroll
    for (int m=0;m<4;++m) af[m] = *(const bf16x8*)(ar + m*16*32);
    #pragma unroll
    for (int n=0;n<4;++n) bg[n] = *(const bf16x8*)(br + n*16*32);
    #pragma unroll
    for (int m=0;m<4;++m)
      #pragma unroll
      for (int n=0;n<4;++n)
        acc[m][n] = __builtin_amdgcn_mfma_f32_16x16x32_bf16(af[m], bg[n], acc[m][n], 0,0,0);
  }
  #pragma unroll
  for (int m=0;m<4;++m){
    const int row = bm + wr*64 + m*16 + lg*4;
    #pragma unroll
    for (int n=0;n<4;++n){
      const int col = bn + wc*64 + n*16 + li;
      #pragma unroll
      for (int r=0;r<4;++r)
        C[(size_t)(row+r)*N + col] = f2bf(acc[m][n][r]);
    }
  }
}

// ---------------- kv_full(bf16) -> rmsnorm+project kv_pt(bf16 pad), rotary k_pe
__global__ __launch_bounds__(256) void build_kvpt(
    const u16* __restrict__ kvfull,  // [S][640], cols 0..575 valid
    const float* __restrict__ gamma, // [512]
    const float* __restrict__ fc, const float* __restrict__ fs, // [S][32]
    u16* __restrict__ kvpt,          // [S][544]
    float* __restrict__ kpe)         // [S][64]
{
  const int s = blockIdx.x, tid = threadIdx.x;
  const int wv = tid>>6, lane = tid&63;
  const u16* src = kvfull + (size_t)s*640;
  __shared__ float red1[4], red2[4];
  float v0 = bf2f(src[tid]), v1 = bf2f(src[tid+256]);
  float sq = v0*v0 + v1*v1;
  #pragma unroll
  for (int off=32; off; off>>=1) sq += __shfl_down(sq, off);
  if (lane==0) red1[wv]=sq;
  __syncthreads();
  float tot = red1[0]+red1[1]+red1[2]+red1[3];
  float rinv = 1.0f/sqrtf(tot*(1.0f/512.0f)+1e-6f);
  float n0 = v0*rinv*gamma[tid], n1 = v1*rinv*gamma[tid+256];
  float s2 = n0*n0+n1*n1;
  #pragma unroll
  for (int off=32; off; off>>=1) s2 += __shfl_down(s2, off);
  if (lane==0) red2[wv]=s2;
  __syncthreads();
  u16* dst = kvpt + (size_t)s*544;
  dst[1+tid]   = f2bf(n0);
  dst[257+tid] = f2bf(n1);
  if (tid==0) dst[0] = f2bf(sqrtf(red2[0]+red2[1]+red2[2]+red2[3]+1.0f));
  if (tid<31) dst[513+tid] = 0;
  if (tid<32){
    float x0 = bf2f(src[512+2*tid]), x1 = bf2f(src[513+2*tid]);
    float c = fc[(size_t)s*32+tid], sn = fs[(size_t)s*32+tid];
    kpe[(size_t)s*64 + 2*tid]   = x0*c - x1*sn;
    kpe[(size_t)s*64 + 2*tid+1] = x0*sn + x1*c;
  }
}

// ---------------- q_raw(bf16) -> rotary + Lorentz project (time NEGATED) ------
__global__ __launch_bounds__(64) void build_qproj(
    const u16* __restrict__ qraw,    // [S][3072]
    const float* __restrict__ fc, const float* __restrict__ fs,
    u16* __restrict__ qp)            // [NH][S][224]
{
  const int s = blockIdx.x, h = blockIdx.y, lane = threadIdx.x;
  const u16* src = qraw + (size_t)s*3072 + h*192;
  u16* dst = qp + ((size_t)h*S_LEN + s)*DPAD;
  u16 e0 = src[lane], e1 = src[lane+64];
  float f0 = bf2f(e0), f1 = bf2f(e1);
  dst[1+lane] = e0; dst[65+lane] = e1;
  float sq = f0*f0 + f1*f1;
  if (lane < 32){
    float x0 = bf2f(src[128+2*lane]), x1 = bf2f(src[129+2*lane]);
    float c = fc[(size_t)s*32+lane], sn = fs[(size_t)s*32+lane];
    float y0 = x0*c - x1*sn, y1 = x0*sn + x1*c;
    dst[129+2*lane] = f2bf(y0); dst[130+2*lane] = f2bf(y1);
    sq += y0*y0 + y1*y1;
  }
  if (lane < 31) dst[193+lane] = 0;
  #pragma unroll
  for (int off=32; off; off>>=1) sq += __shfl_down(sq, off);
  if (lane==0) dst[0] = f2bf(-sqrtf(sq+1.0f));   // Minkowski sign folded in
}

// ---------------- kvb(bf16) -> k_proj [NH][S][224], v_projT [NH][128][S] ------
__global__ __launch_bounds__(64) void build_kvproj(
    const u16* __restrict__ kvb,   // [S][4096], head h at cols h*255..+254
    const float* __restrict__ kpe, // [S][64]
    u16* __restrict__ kp,          // [NH][S][224]
    u16* __restrict__ vt)          // [NH][128][S]
{
  const int s = blockIdx.x, h = blockIdx.y, lane = threadIdx.x;
  const u16* src = kvb + (size_t)s*4096 + h*255;
  u16* kdst = kp + ((size_t)h*S_LEN + s)*DPAD;
  u16 a0 = src[lane], a1 = src[lane+64];
  float fa0 = bf2f(a0), fa1 = bf2f(a1);
  float pe = kpe[(size_t)s*64 + lane];
  kdst[1+lane] = a0; kdst[65+lane] = a1; kdst[129+lane] = f2bf(pe);
  if (lane<31) kdst[193+lane] = 0;
  float sq = fa0*fa0 + fa1*fa1 + pe*pe;
  #pragma unroll
  for (int off=32; off; off>>=1) sq += __shfl_down(sq, off);
  if (lane==0) kdst[0] = f2bf(sqrtf(sq+1.0f));
  // V (127 vals) -> project -> transposed store
  u16 b0 = src[128+lane];
  u16 b1 = (lane<63) ? src[192+lane] : (u16)0;
  float fb0 = bf2f(b0), fb1 = bf2f(b1);
  u16* vbase = vt + (size_t)h*128*S_LEN;
  vbase[(size_t)(1+lane)*S_LEN + s] = b0;
  if (lane<63) vbase[(size_t)(65+lane)*S_LEN + s] = b1;
  float sv = fb0*fb0 + fb1*fb1;
  #pragma unroll
  for (int off=32; off; off>>=1) sv += __shfl_down(sv, off);
  if (lane==0) vbase[s] = f2bf(sqrtf(sv+1.0f));
}

// ---------------- MFMA flash attention + Lorentz centroid epilogue ------------
// 4 independent waves/block, 16 q-rows each; 32-key tiles; no __syncthreads.
__global__ __launch_bounds__(256) void attn_mfma(
    const u16* __restrict__ qp,   // [NH][S][224] (time negated)
    const u16* __restrict__ kp,   // [NH][S][224]
    const u16* __restrict__ vt,   // [NH][128][S]
    const float* __restrict__ ss,
    u16* __restrict__ out)        // [S][2048] bf16
{
  const int h = blockIdx.y;
  const int w = threadIdx.x >> 6, lane = threadIdx.x & 63;
  const int lg = lane >> 4, li = lane & 15;
  const int r0 = blockIdx.x*64 + w*16;
  const float cl2 = (2.0f / ss[0]) * 1.44269504088896f;  // 2/scale * log2(e)
  __shared__ __align__(16) u16 P[4][16][40];             // per-wave P transpose

  const u16* qb = qp + ((size_t)h*S_LEN + r0 + li)*DPAD + lg*8;
  bf16x8 qf[7];
  #pragma unroll
  for (int d=0; d<7; ++d) qf[d] = *(const bf16x8*)(qb + d*32);

  f32x4 of[8];
  #pragma unroll
  for (int d=0; d<8; ++d) of[d] = (f32x4){0.f,0.f,0.f,0.f};
  float mreg[4] = {-3e38f,-3e38f,-3e38f,-3e38f};
  float lreg[4] = {0.f,0.f,0.f,0.f};

  const int tmax = (r0 + 15) >> 5;
  for (int t=0; t<=tmax; ++t){
    const int k0 = t*32;
    const u16* kb = kp + ((size_t)h*S_LEN + k0 + li)*DPAD + lg*8;
    f32x4 s0 = (f32x4){0.f,0.f,0.f,0.f}, s1 = (f32x4){0.f,0.f,0.f,0.f};
    #pragma unroll
    for (int d=0; d<7; ++d){
      bf16x8 kf0 = *(const bf16x8*)(kb + d*32);
      bf16x8 kf1 = *(const bf16x8*)(kb + 16*DPAD + d*32);
      s0 = __builtin_amdgcn_mfma_f32_16x16x32_bf16(qf[d], kf0, s0, 0,0,0);
      s1 = __builtin_amdgcn_mfma_f32_16x16x32_bf16(qf[d], kf1, s1, 0,0,0);
    }
    float alpha[4];
    #pragma unroll
    for (int r=0; r<4; ++r){
      const int row = r0 + lg*4 + r;
      float a = (k0 + li      <= row) ? s0[r] : -3e38f;   // causal mask
      float b = (k0 + 16 + li <= row) ? s1[r] : -3e38f;
      float mx = fmaxf(a,b);
      mx = fmaxf(mx, __shfl_xor(mx,1));
      mx = fmaxf(mx, __shfl_xor(mx,2));
      mx = fmaxf(mx, __shfl_xor(mx,4));
      mx = fmaxf(mx, __shfl_xor(mx,8));
      float mn = fmaxf(mreg[r], mx);
      alpha[r] = exp2f((mreg[r]-mn)*cl2);
      mreg[r] = mn;
      float e0 = exp2f((a-mn)*cl2);
      float e1 = exp2f((b-mn)*cl2);
      float ls = e0 + e1;
      ls += __shfl_xor(ls,1);
      ls += __shfl_xor(ls,2);
      ls += __shfl_xor(ls,4);
      ls += __shfl_xor(ls,8);
      lreg[r] = lreg[r]*alpha[r] + ls;
      P[w][lg*4+r][li]    = f2bf(e0);
      P[w][lg*4+r][li+16] = f2bf(e1);
    }
    #pragma unroll
    for (int d=0; d<8; ++d){
      of[d][0]*=alpha[0]; of[d][1]*=alpha[1];
      of[d][2]*=alpha[2]; of[d][3]*=alpha[3];
    }
    bf16x8 pa = *(const bf16x8*)(&P[w][li][lg*8]);   // same-wave LDS transpose
    const u16* vb = vt + ((size_t)h*128 + li)*S_LEN + k0 + lg*8;
    #pragma unroll
    for (int d=0; d<8; ++d){
      bf16x8 vf = *(const bf16x8*)(vb + (size_t)d*16*S_LEN);
      of[d] = __builtin_amdgcn_mfma_f32_16x16x32_bf16(pa, vf, of[d], 0,0,0);
    }
  }
  // epilogue: ave = O/l ; cen = ave / sqrt(clip(|Minkowski(ave)|,1e-8))
  #pragma unroll
  for (int r=0; r<4; ++r){
    float linv = 1.0f / lreg[r];
    float av[8]; float part = 0.f;
    #pragma unroll
    for (int d=0; d<8; ++d){ float a = of[d][r]*linv; av[d]=a; part += a*a; }
    if (li==0) part -= 2.f*av[0]*av[0];   // d==0 is the time component
    part += __shfl_xor(part,1);
    part += __shfl_xor(part,2);
    part += __shfl_xor(part,4);
    part += __shfl_xor(part,8);
    float sc = 1.0f / sqrtf(fmaxf(fabsf(part), 1e-8f));
    u16* ob = out + (size_t)(r0 + lg*4 + r)*2048 + h*128 + li;
    #pragma unroll
    for (int d=0; d<8; ++d) ob[d*16] = f2bf(av[d]*sc);
  }
}

// ---------------- final projection: out = [sqrt(|y|^2+1), y] (f32 out) --------
__global__ __launch_bounds__(256) void final_project(
    const u16* __restrict__ y,  // [S][2048], cols 0..2046 valid
    float* __restrict__ out)    // [S][2048]
{
  const int s = blockIdx.x, tid = threadIdx.x;
  const int wv = tid>>6, lane = tid&63;
  const u16* src = y + (size_t)s*2048;
  float* dst = out + (size_t)s*2048;
  float sq = 0.f;
  for (int j=tid; j<2047; j+=256){
    float v = bf2f(src[j]);
    dst[1+j] = v;
    sq += v*v;
  }
  __shared__ float red[4];
  #pragma unroll
  for (int off=32; off; off>>=1) sq += __shfl_down(sq, off);
  if (lane==0) red[wv]=sq;
  __syncthreads();
  if (tid==0) dst[0] = sqrtf(red[0]+red[1]+red[2]+red[3]+1.0f);
}

extern "C" void kernel_launch(void* const* d_in, const int* in_sizes, int n_in,
                              void* d_out, int out_size, void* d_ws, size_t ws_size,
                              hipStream_t stream) {
  const float* x    = (const float*)d_in[0];
  const float* fc   = (const float*)d_in[2];
  const float* fs   = (const float*)d_in[3];
  const float* wq   = (const float*)d_in[5];
  const float* wkva = (const float*)d_in[6];
  const float* gam  = (const float*)d_in[7];
  const float* wkvb = (const float*)d_in[8];
  const float* wo   = (const float*)d_in[9];
  const float* ssp  = (const float*)d_in[10];
  float* out = (float*)d_out;
  char* base = (char*)d_ws;

  // workspace layout (bytes), total ~95.9 MiB
  u16*   xb     = (u16*)(base + 0);           //  8,388,608  x bf16 [2048][2048]
  u16*   wqT    = (u16*)(base + 8388608);     // 12,582,912  [3072][2048] (reused: woT)
  u16*   wkvaT  = (u16*)(base + 20971520);    //  2,621,440  [640][2048]
  u16*   wkvbT  = (u16*)(base + 23592960);    //  4,456,448  [4096][544]
  u16*   qraw   = (u16*)(base + 28049408);    // 12,582,912  [2048][3072] (reused: attn_o)
  u16*   kvfull = (u16*)(base + 40632320);    //  2,621,440  [2048][640]
  u16*   kvpt   = (u16*)(base + 43253760);    //  2,228,224  [2048][544]
  float* kpe    = (float*)(base + 45481984);  //    524,288  [2048][64]
  u16*   kvb    = (u16*)(base + 46006272);    // 16,777,216  [2048][4096] (reused: y)
  u16*   qproj  = (u16*)(base + 62783488);    // 14,680,064  [16][2048][224]
  u16*   kproj  = (u16*)(base + 77463552);    // 14,680,064  [16][2048][224]
  u16*   vprojT = (u16*)(base + 92143616);    //  8,388,608  [16][128][2048]
  u16*   attn_o = qraw;
  u16*   yb     = kvb;
  u16*   woT    = wqT;

  dim3 tb(32,8);
  cast_bf16x8<<<2048, 256, 0, stream>>>(x, xb);
  transpose_cast<<<dim3(64,96),  tb, 0, stream>>>(wq,   wqT,   2048, 3072, 3072, 2048);
  transpose_cast<<<dim3(64,20),  tb, 0, stream>>>(wkva, wkvaT, 2048,  576,  640, 2048);
  gemm_bf16<<<dim3(24,16), 256, 0, stream>>>(xb, wqT,   qraw,   2048, 3072, 2048);
  gemm_bf16<<<dim3(5,16),  256, 0, stream>>>(xb, wkvaT, kvfull, 2048,  640, 2048);
  build_kvpt<<<2048, 256, 0, stream>>>(kvfull, gam, fc, fs, kvpt, kpe);
  transpose_cast<<<dim3(17,128), tb, 0, stream>>>(wkvb, wkvbT,  513, 4080, 4096,  544);
  gemm_bf16<<<dim3(32,16), 256, 0, stream>>>(kvpt, wkvbT, kvb,  2048, 4096,  544);
  build_qproj<<<dim3(2048,16), 64, 0, stream>>>(qraw, fc, fs, qproj);
  build_kvproj<<<dim3(2048,16), 64, 0, stream>>>(kvb, kpe, kproj, vprojT);
  attn_mfma<<<dim3(32,16), 256, 0, stream>>>(qproj, kproj, vprojT, ssp, attn_o);
  transpose_cast<<<dim3(64,64), tb, 0, stream>>>(wo, woT, 2048, 2047, 2048, 2048);
  gemm_bf16<<<dim3(16,16), 256, 0, stream>>>(attn_o, woT, yb, 2048, 2048, 2048);
  final_project<<<2048, 256, 0, stream>>>(yb, out);
}